// Round 5
// baseline (150.685 us; speedup 1.0000x reference)
//
#include <hip/hip_runtime.h>

#define N_SIG 2048
#define NT    32            // 2048/64 tiles per dimension
#define N_OFFDIAG_BLOCKS 992   // (32*31/2) tiles * 2 half-blocks
#define N_PAIR_BLOCKS 1024     // 992 off-diag halves + 32 full diagonal tiles
                               // == exactly 4 blocks/CU * 256 CUs at VGPR<=128
#define DV_FLOATS   (N_SIG * 8)
#define PART_FLOATS (32 * 64 * 9 * 64)   // [group][slot][q][sig] partial sums

__device__ __forceinline__ float frcp(float x) { return __builtin_amdgcn_rcpf(x); }

// erf(y / sqrt(2)) — Abramowitz–Stegun 7.1.26 with sqrt2 folded in, |err| < 1.5e-7
__device__ __forceinline__ float erf_div_sqrt2(float y) {
    const float ay = fabsf(y);
    const float t  = frcp(fmaf(0.23164454f, ay, 1.f));   // p/sqrt2, p = 0.3275911
    const float p  = t * fmaf(t, fmaf(t, fmaf(t, fmaf(t, 1.061405429f, -1.453152027f),
                                              1.421413741f), -0.284496736f), 0.254829592f);
    const float e  = __expf(-0.5f * ay * ay);
    return copysignf(fmaf(-p, e, 1.f), y);
}

// ---------------- Kernel 1: per-signal derived quantities (+ zero acc in atomic mode) ----
template<bool ZERO_ACC>
__global__ void derive_k(const float* __restrict__ p, float* __restrict__ dv,
                         float* __restrict__ acc) {
    int j = blockIdx.x * blockDim.x + threadIdx.x;
    if (j >= N_SIG) return;
    if constexpr (ZERO_ACC) {
        #pragma unroll
        for (int k = 0; k < 9; k++) acc[j * 9 + k] = 0.f;
    }
    const float* pj = p + j * 15;
    float m1 = pj[0] * 95.f + 5.f, m2 = pj[1] * 95.f + 5.f;
    float mc = powf(m1 * m2, 0.6f) / powf(m1 + m2, 0.2f);
    float fisco = 220.f / (m1 + m2);
    float dist = pj[2] * 2950.f + 50.f;
    float4* o = (float4*)(dv + j * 8);
    o[0] = make_float4(pj[5], pj[3], pj[4], mc);   // t, ra, dec, mc
    o[1] = make_float4(fisco, dist, pj[7], 0.f);   // fisco, dist, psi, pad
}

// ---------------- Kernel 2: symmetric pair tiles (R2 structure restored) ----------------
// LESSONS: R3 (scalar weights) -> VGPR 52, serialization, 53us. R4 (dual-column)
// -> VGPR 140 > 128 -> 3 blocks/CU -> 1.33x fill penalty, 48us. R2 (this
// structure) = 37us, VGPR 128, 4 blocks/CU, perfect 1024-block fill. VALU-issue
// time is ~28us across all variants => compute-bound; changes here only trim
// work/stalls without raising register pressure:
//  - columns read from GLOBAL (dv is 64KB, 2KB/block window -> L1-resident;
//    moves 2 reads/pair from LDS pipe to idle VMEM pipe, drops sCol staging)
//  - s1 = Bsum + sum_q csum_q*f_q (precomputed col-sums; kills the 16-add
//    dependent reduction chain in the GEMV loop)
template<bool USE_PART>
__global__ __launch_bounds__(256) void pair_k(
    const float* __restrict__ dv,
    const float* __restrict__ iw1, const float* __restrict__ ib1,
    const float* __restrict__ ig1, const float* __restrict__ ibt1,
    const float* __restrict__ iw2,
    float* __restrict__ acc)   // part (part mode) or acc (atomic mode)
{
    __shared__ __align__(16) float sW1[128];   // iw1 [16][8]
    __shared__ __align__(16) float sEC[64];    // per-h (b1, g1, bt1, 0.5*w2)
    __shared__ __align__(16) float sCS[12];    // csum[8], bsum, pad
    __shared__ float partR[9 * 256];           // [q][wave][lane]
    __shared__ float partC[USE_PART ? 9 * 256 : 1];

    // ---- tile decode: 992 off-diag half-blocks, then 32 full diag blocks ----
    const int b = blockIdx.x;
    int ti, tj, half;
    bool diag;
    if (b < N_OFFDIAG_BLOCKS) {
        const int tileId = b >> 1;
        half = b & 1;
        int k = tileId, row = 0;
        while (k >= NT - 1 - row) { k -= NT - 1 - row; row++; }
        ti = row; tj = row + 1 + k;
        diag = false;
    } else {
        ti = tj = b - N_OFFDIAG_BLOCKS;
        half = 0;
        diag = true;
    }
    const int rbase = ti * 64, cbase = tj * 64;

    const int tid = threadIdx.x;
    const float4* dv4 = (const float4*)dv;

    if (tid < 128) sW1[tid] = iw1[tid];
    else if (tid < 144) {
        int h = tid - 128;
        sEC[h * 4 + 0] = ib1[h]; sEC[h * 4 + 1] = ig1[h];
        sEC[h * 4 + 2] = ibt1[h]; sEC[h * 4 + 3] = 0.5f * iw2[h];
    } else if (tid < 156) {
        int q = tid - 144;
        float s = 0.f;
        if (q < 8)       { for (int h = 0; h < 16; h++) s += iw1[h * 8 + q]; }
        else if (q == 8) { for (int h = 0; h < 16; h++) s += ib1[h]; }
        sCS[q] = s;
    }
    __syncthreads();

    const int w = tid >> 6, l = tid & 63;
    const int gi = rbase + l;
    const float4 r0 = dv4[gi * 2], r1 = dv4[gi * 2 + 1];
    const float ti_ = r0.x, rai = r0.y, deci = r0.z, mci = r0.w;
    const float fi = r1.x, disti = r1.y, psii = r1.z;

    // off-diag: vwave V=half*4+w covers s in {V+8t}, t=0..7 -> s 0..63 over 8 vwaves
    // diag:     wave w covers s in {w+1+4t}, t=0..7         -> s 1..32 over 4 waves
    const int sstep = diag ? 4 : 8;
    const int sbase = diag ? (w + 1) : (half * 4 + w);

    float rowacc[9], colacc[9];
    #pragma unroll
    for (int q = 0; q < 9; q++) { rowacc[q] = 0.f; colacc[q] = 0.f; }

    const float4* sW4  = (const float4*)sW1;
    const float4* sEC4 = (const float4*)sEC;
    const float4* sCS4 = (const float4*)sCS;

    for (int t = 0; t < 8; t++) {
        const int s  = sbase + sstep * t;
        const int dj = (l + s) & 63;
        const float4 c0 = dv4[(cbase + dj) * 2];
        const float4 c1 = dv4[(cbase + dj) * 2 + 1];

        // ---- symmetric pairwise features ----
        const float dra  = fabsf(rai - c0.y), ddec = fabsf(deci - c0.z);
        float f[8];
        f[0] = fabsf(ti_ - c0.x);
        f[1] = __builtin_amdgcn_sqrtf(fmaf(dra, dra, ddec * ddec));
        f[2] = frcp(fmaf(fabsf(mci - c0.w), 0.033333333f, 1.f));
        f[3] = __expf(fabsf(fi - c1.x) * -0.01f);
        f[4] = fminf(disti, c1.y) * frcp(fmaxf(disti, c1.y));
        f[5] = fabsf(psii - c1.z);
        f[6] = dra; f[7] = ddec;

        // ---- s1 from precomputed column sums (independent of GEMV chain) ----
        const float4 cs0 = sCS4[0], cs1 = sCS4[1];
        float s1 = sCS[8];
        s1 = fmaf(cs0.x, f[0], s1); s1 = fmaf(cs0.y, f[1], s1);
        s1 = fmaf(cs0.z, f[2], s1); s1 = fmaf(cs0.w, f[3], s1);
        s1 = fmaf(cs1.x, f[4], s1); s1 = fmaf(cs1.y, f[5], s1);
        s1 = fmaf(cs1.z, f[6], s1); s1 = fmaf(cs1.w, f[7], s1);

        // ---- 8->16 GEMV + fused second moment ----
        float z[16];
        float s2 = 0.f;
        #pragma unroll
        for (int h = 0; h < 16; h++) {
            const float4 w0 = sW4[h * 2];
            const float4 w1 = sW4[h * 2 + 1];
            float zv = sEC4[h].x;
            zv = fmaf(w0.x, f[0], zv); zv = fmaf(w0.y, f[1], zv);
            zv = fmaf(w0.z, f[2], zv); zv = fmaf(w0.w, f[3], zv);
            zv = fmaf(w1.x, f[4], zv); zv = fmaf(w1.y, f[5], zv);
            zv = fmaf(w1.z, f[6], zv); zv = fmaf(w1.w, f[7], zv);
            z[h] = zv;
            s2 = fmaf(zv, zv, s2);
        }
        const float mu  = s1 * 0.0625f;
        const float var = fmaf(-mu, mu, s2 * 0.0625f);
        const float inv = __builtin_amdgcn_rsqf(var + 1e-5f);

        // ---- GELU(erf) + dot(iw2) ----
        float logit = 0.f;
        #pragma unroll
        for (int h = 0; h < 16; h++) {
            const float4 c = sEC4[h];  // (b, g, bt, 0.5*w2)
            const float y = fmaf((z[h] - mu) * inv, c.y, c.z);
            logit = fmaf(y * c.w, 1.f + erf_div_sqrt2(y), logit);
        }
        float e = __expf(logit);
        // diag tile: s=32 pairs appear twice (lane a and lane a+32) -> keep half
        if (diag && s == 32 && l >= 32) e = 0.f;

        rowacc[8] += e; colacc[8] += e;
        #pragma unroll
        for (int q = 0; q < 8; q++) {
            rowacc[q] = fmaf(e, f[q], rowacc[q]);
            colacc[q] = fmaf(e, f[q], colacc[q]);
        }
        // rotate col accumulator so lane l tracks column (l + s_next) & 63
        if (t + 1 < 8) {
            const int src = (l + sstep) & 63;
            #pragma unroll
            for (int q = 0; q < 9; q++) colacc[q] = __shfl(colacc[q], src);
        }
    }

    const int s_last = sbase + sstep * 7;
    const int cfin = (l + s_last) & 63;   // true column index of colacc

    if constexpr (USE_PART) {
        // ---- single barrier: stage both sides in LDS, then coalesced plain stores ----
        #pragma unroll
        for (int q = 0; q < 9; q++) partR[q * 256 + w * 64 + l]    = rowacc[q];
        #pragma unroll
        for (int q = 0; q < 9; q++) partC[q * 256 + w * 64 + cfin] = colacc[q];
        __syncthreads();
        if (tid < 192) {
            const int sig = tid & 63;
            // slot bijection per group: row side of (ti,tj,half) -> group ti slot 2*tj+half
            //                           col side               -> group tj slot 2*ti+1-half
            // diag (half=0): slots 2g and 2g+1.  Union over all tiles = exactly 0..63.
            float* __restrict__ pr = acc + ((ti * 64 + (2 * tj + half)) * 9) * 64;
            float* __restrict__ pc = acc + ((tj * 64 + (2 * ti + 1 - half)) * 9) * 64;
            #pragma unroll
            for (int r = 0; r < 3; r++) {
                const int q = (tid >> 6) * 3 + r;
                const float* ppR = partR + q * 256 + sig;
                pr[q * 64 + sig] = ppR[0] + ppR[64] + ppR[128] + ppR[192];
                const float* ppC = partC + q * 256 + sig;
                pc[q * 64 + sig] = ppC[0] + ppC[64] + ppC[128] + ppC[192];
            }
        }
    } else {
        // ---- fallback: atomic scatter (two phases) ----
        const int stag = b & 63;
        #pragma unroll
        for (int q = 0; q < 9; q++) partR[q * 256 + w * 64 + l] = rowacc[q];
        __syncthreads();
        if (tid < 192) {
            const int sig = (tid + stag) & 63;
            #pragma unroll
            for (int r = 0; r < 3; r++) {
                const int q = (tid >> 6) * 3 + r;
                const float* pp = partR + q * 256 + sig;
                unsafeAtomicAdd(&acc[(rbase + sig) * 9 + q], pp[0] + pp[64] + pp[128] + pp[192]);
            }
        }
        __syncthreads();
        #pragma unroll
        for (int q = 0; q < 9; q++) partR[q * 256 + w * 64 + cfin] = colacc[q];
        __syncthreads();
        if (tid < 192) {
            const int sig = (tid + stag) & 63;
            #pragma unroll
            for (int r = 0; r < 3; r++) {
                const int q = (tid >> 6) * 3 + r;
                const float* pp = partR + q * 256 + sig;
                unsafeAtomicAdd(&acc[(cbase + sig) * 9 + q], pp[0] + pp[64] + pp[128] + pp[192]);
            }
        }
    }
}

// ---------------- Kernel 3 (part mode): fused slot-reduce + overlap net ----------------
// One block per 64-signal group: the group's [64 slot][9 q][64 sig] panel is
// CONTIGUOUS -> 256 threads stream it fully coalesced (cells t, t+256, t+512),
// reduce over slots into red[576], then run the overlap net for 64 signals
// in 8 passes of 8 signals (one 32-lane group per signal).
__global__ __launch_bounds__(256) void outfused_k(
    const float* __restrict__ part,
    const float* __restrict__ ow1, const float* __restrict__ ob1,
    const float* __restrict__ og1, const float* __restrict__ obt1,
    const float* __restrict__ ow2, const float* __restrict__ ob2,
    float* __restrict__ out)
{
    __shared__ float red[576];        // [q][sig] reduced sums
    __shared__ float sOw1[32 * 9];    // ow1 padded [h][9] (9 coprime 32 -> conflict-free)
    __shared__ float sOw2T[32 * 16];  // ow2 transposed [k][o]
    __shared__ float sB1[32], sG[32], sBt[32], sB2[16];
    __shared__ float h2s[8 * 33];     // per-group hidden, pad 33

    const int g = blockIdx.x;
    const int tid = threadIdx.x;

    // stage small weights
    { int h = tid >> 3, f = tid & 7; sOw1[h * 9 + f] = ow1[tid]; }          // 256 = 32*8
    { int o = tid >> 5, k = tid & 31; sOw2T[k * 16 + o] = ow2[tid]; }       // first 256 of 512
    { int idx = tid + 256; int o = idx >> 5, k = idx & 31; sOw2T[k * 16 + o] = ow2[idx]; }
    if (tid < 32) { sB1[tid] = ob1[tid]; sG[tid] = og1[tid]; sBt[tid] = obt1[tid]; }
    if (tid < 16) sB2[tid] = ob2[tid];

    // coalesced streaming reduction over 64 slots
    const float* bp = part + g * (64 * 576);
    float a0 = 0.f, a1 = 0.f, a2 = 0.f;
    #pragma unroll 4
    for (int slot = 0; slot < 64; ++slot) {
        const float* ps = bp + slot * 576;
        a0 += ps[tid];
        a1 += ps[tid + 256];
        if (tid < 64) a2 += ps[tid + 512];
    }
    red[tid] = a0; red[tid + 256] = a1; if (tid < 64) red[tid + 512] = a2;
    __syncthreads();

    const int grp = tid >> 5;   // 0..7 : one signal per 32-lane group per pass
    const int h   = tid & 31;

    for (int pass = 0; pass < 8; ++pass) {
        const int sig = pass * 8 + grp;
        const float invL = frcp(red[8 * 64 + sig]);
        float z2 = sB1[h];
        #pragma unroll
        for (int f = 0; f < 8; f++)
            z2 = fmaf(sOw1[h * 9 + f], red[f * 64 + sig] * invL, z2);
        float mu = z2;
        #pragma unroll
        for (int off = 16; off > 0; off >>= 1) mu += __shfl_xor(mu, off);
        mu *= (1.f / 32.f);
        const float d = z2 - mu;
        float var = d * d;
        #pragma unroll
        for (int off = 16; off > 0; off >>= 1) var += __shfl_xor(var, off);
        var *= (1.f / 32.f);
        const float y = d * __builtin_amdgcn_rsqf(var + 1e-5f) * sG[h] + sBt[h];
        h2s[grp * 33 + h] = 0.5f * y * (1.f + erf_div_sqrt2(y));
        __syncthreads();
        if (h < 16) {
            float o = sB2[h];
            #pragma unroll
            for (int k = 0; k < 32; k++)
                o = fmaf(sOw2T[k * 16 + h], h2s[grp * 33 + k], o);
            out[(g * 64 + sig) * 16 + h] = o;
        }
        __syncthreads();
    }
}

// ---------------- Kernel 3 (fallback mode): overlap net per row off acc[2048][9] ----
__global__ void out_k(const float* __restrict__ acc,
                      const float* __restrict__ ow1, const float* __restrict__ ob1,
                      const float* __restrict__ og1, const float* __restrict__ obt1,
                      const float* __restrict__ ow2, const float* __restrict__ ob2,
                      float* __restrict__ out)
{
    __shared__ float h2s[32];
    const int i = blockIdx.x, t = threadIdx.x;   // 64 threads
    if (t < 32) {
        const float invL = frcp(acc[i * 9 + 8]);
        float z2 = ob1[t];
        #pragma unroll
        for (int f = 0; f < 8; f++) z2 = fmaf(ow1[t * 8 + f], acc[i * 9 + f] * invL, z2);
        float mu = z2;
        #pragma unroll
        for (int off = 16; off > 0; off >>= 1) mu += __shfl_xor(mu, off);
        mu *= (1.f / 32.f);
        const float d = z2 - mu;
        float var = d * d;
        #pragma unroll
        for (int off = 16; off > 0; off >>= 1) var += __shfl_xor(var, off);
        var *= (1.f / 32.f);
        const float y = d * __builtin_amdgcn_rsqf(var + 1e-5f) * og1[t] + obt1[t];
        h2s[t] = 0.5f * y * (1.f + erf_div_sqrt2(y));
    }
    __syncthreads();
    if (t < 16) {
        float o = ob2[t];
        #pragma unroll
        for (int k = 0; k < 32; k++) o = fmaf(ow2[t * 32 + k], h2s[k], o);
        out[i * 16 + t] = o;
    }
}

extern "C" void kernel_launch(void* const* d_in, const int* in_sizes, int n_in,
                              void* d_out, int out_size, void* d_ws, size_t ws_size,
                              hipStream_t stream) {
    const float* p    = (const float*)d_in[0];
    const float* iw1  = (const float*)d_in[1];
    const float* ib1  = (const float*)d_in[2];
    const float* ig1  = (const float*)d_in[3];
    const float* ibt1 = (const float*)d_in[4];
    const float* iw2  = (const float*)d_in[5];
    // d_in[6] = ib2: uniform logit offset, softmax-invariant -> unused
    const float* ow1  = (const float*)d_in[7];
    const float* ob1  = (const float*)d_in[8];
    const float* og1  = (const float*)d_in[9];
    const float* obt1 = (const float*)d_in[10];
    const float* ow2  = (const float*)d_in[11];
    const float* ob2  = (const float*)d_in[12];

    float* dv = (float*)d_ws;                  // [2048][8]
    const bool use_part = ws_size >= (size_t)(DV_FLOATS + PART_FLOATS) * sizeof(float);

    if (use_part) {
        float* part = dv + DV_FLOATS;          // [32][64][9][64] partial sums
        derive_k<false><<<N_SIG / 256, 256, 0, stream>>>(p, dv, nullptr);
        pair_k<true><<<N_PAIR_BLOCKS, 256, 0, stream>>>(dv, iw1, ib1, ig1, ibt1, iw2, part);
        outfused_k<<<32, 256, 0, stream>>>(part, ow1, ob1, og1, obt1, ow2, ob2,
                                           (float*)d_out);
    } else {
        float* acc = dv + DV_FLOATS;           // [2048][9]
        derive_k<true><<<N_SIG / 256, 256, 0, stream>>>(p, dv, acc);
        pair_k<false><<<N_PAIR_BLOCKS, 256, 0, stream>>>(dv, iw1, ib1, ig1, ibt1, iw2, acc);
        out_k<<<N_SIG, 64, 0, stream>>>(acc, ow1, ob1, og1, obt1, ow2, ob2,
                                        (float*)d_out);
    }
}

// Round 6
// 137.012 us; speedup vs baseline: 1.0998x; 1.0998x over previous
//
#include <hip/hip_runtime.h>

#define N_SIG 2048
#define NT    32            // 2048/64 tiles per dimension
#define N_OFFDIAG_BLOCKS 992   // (32*31/2) tiles * 2 half-blocks
#define N_PAIR_BLOCKS 1024     // 992 off-diag halves + 32 full diagonal tiles
                               // == exactly 4 blocks/CU * 256 CUs at VGPR<=128
#define DV_FLOATS   (N_SIG * 8)
#define PART_FLOATS (32 * 64 * 9 * 64)   // [group][slot][q][sig] partial sums

__device__ __forceinline__ float frcp(float x) { return __builtin_amdgcn_rcpf(x); }

// erf(y / sqrt(2)) — Abramowitz–Stegun 7.1.26 with sqrt2 folded in, |err| < 1.5e-7
__device__ __forceinline__ float erf_div_sqrt2(float y) {
    const float ay = fabsf(y);
    const float t  = frcp(fmaf(0.23164454f, ay, 1.f));   // p/sqrt2, p = 0.3275911
    const float p  = t * fmaf(t, fmaf(t, fmaf(t, fmaf(t, 1.061405429f, -1.453152027f),
                                              1.421413741f), -0.284496736f), 0.254829592f);
    const float e  = __expf(-0.5f * ay * ay);
    return copysignf(fmaf(-p, e, 1.f), y);
}

// ---------------- Kernel 1: per-signal derived quantities (+ zero acc in atomic mode) ----
template<bool ZERO_ACC>
__global__ void derive_k(const float* __restrict__ p, float* __restrict__ dv,
                         float* __restrict__ acc) {
    int j = blockIdx.x * blockDim.x + threadIdx.x;
    if (j >= N_SIG) return;
    if constexpr (ZERO_ACC) {
        #pragma unroll
        for (int k = 0; k < 9; k++) acc[j * 9 + k] = 0.f;
    }
    const float* pj = p + j * 15;
    float m1 = pj[0] * 95.f + 5.f, m2 = pj[1] * 95.f + 5.f;
    float mc = powf(m1 * m2, 0.6f) / powf(m1 + m2, 0.2f);
    float fisco = 220.f / (m1 + m2);
    float dist = pj[2] * 2950.f + 50.f;
    float4* o = (float4*)(dv + j * 8);
    o[0] = make_float4(pj[5], pj[3], pj[4], mc);   // t, ra, dec, mc
    o[1] = make_float4(fisco, dist, pj[7], 0.f);   // fisco, dist, psi, pad
}

// ---------------- Kernel 2: symmetric pair tiles (EXACT R2 body) ----------------
// REGALLOC CLIFF LOG — do not "improve" this loop without re-checking VGPR:
//   R2 (this body):           VGPR 128 -> 4 blocks/CU, perfect 1024 fill, ~37us
//   R3 scalar-load weights:   VGPR 52, serialized, 53us
//   R4 dual-column:           VGPR 140 -> 3 blocks/CU, 1.33x fill tax, 48us
//   R5 global cols + csum-s1: VGPR 136 -> 3 blocks/CU, 49us
// VALU-issue is ~28us in every variant; only occupancy x fill ever moved the time.
// NOTE: no min-waves arg! (256,4) capped VGPR at 128 -> allocator squeezed to 64
// -> spill -> 1.1 GB HBM scratch traffic (prior session rounds 5/6).
template<bool USE_PART>
__global__ __launch_bounds__(256) void pair_k(
    const float* __restrict__ dv,
    const float* __restrict__ iw1, const float* __restrict__ ib1,
    const float* __restrict__ ig1, const float* __restrict__ ibt1,
    const float* __restrict__ iw2,
    float* __restrict__ acc)   // part (part mode) or acc (atomic mode)
{
    __shared__ float4 sColA[64], sColB[64];
    __shared__ __align__(16) float sW1[128];   // iw1 [16][8]
    __shared__ __align__(16) float sEC[64];    // per-h (b1, g1, bt1, 0.5*w2)
    __shared__ float partR[9 * 256];           // [q][wave][lane]
    __shared__ float partC[USE_PART ? 9 * 256 : 1];

    // ---- tile decode: 992 off-diag half-blocks, then 32 full diag blocks ----
    const int b = blockIdx.x;
    int ti, tj, half;
    bool diag;
    if (b < N_OFFDIAG_BLOCKS) {
        const int tileId = b >> 1;
        half = b & 1;
        int k = tileId, row = 0;
        while (k >= NT - 1 - row) { k -= NT - 1 - row; row++; }
        ti = row; tj = row + 1 + k;
        diag = false;
    } else {
        ti = tj = b - N_OFFDIAG_BLOCKS;
        half = 0;
        diag = true;
    }
    const int rbase = ti * 64, cbase = tj * 64;

    const int tid = threadIdx.x;
    const float4* dv4 = (const float4*)dv;

    if (tid < 64)  { sColA[tid] = dv4[(cbase + tid) * 2]; sColB[tid] = dv4[(cbase + tid) * 2 + 1]; }
    if (tid >= 64 && tid < 192) sW1[tid - 64] = iw1[tid - 64];
    if (tid >= 192 && tid < 208) {
        int h = tid - 192;
        sEC[h * 4 + 0] = ib1[h]; sEC[h * 4 + 1] = ig1[h];
        sEC[h * 4 + 2] = ibt1[h]; sEC[h * 4 + 3] = 0.5f * iw2[h];
    }
    __syncthreads();

    const int w = tid >> 6, l = tid & 63;
    const int gi = rbase + l;
    const float4 r0 = dv4[gi * 2], r1 = dv4[gi * 2 + 1];
    const float ti_ = r0.x, rai = r0.y, deci = r0.z, mci = r0.w;
    const float fi = r1.x, disti = r1.y, psii = r1.z;

    // off-diag: vwave V=half*4+w covers s in {V+8t}, t=0..7 -> s 0..63 over 8 vwaves
    // diag:     wave w covers s in {w+1+4t}, t=0..7         -> s 1..32 over 4 waves
    const int sstep = diag ? 4 : 8;
    const int sbase = diag ? (w + 1) : (half * 4 + w);

    float rowacc[9], colacc[9];
    #pragma unroll
    for (int q = 0; q < 9; q++) { rowacc[q] = 0.f; colacc[q] = 0.f; }

    const float4* sW4  = (const float4*)sW1;
    const float4* sEC4 = (const float4*)sEC;

    for (int t = 0; t < 8; t++) {
        const int s  = sbase + sstep * t;
        const int dj = (l + s) & 63;
        const float4 c0 = sColA[dj], c1 = sColB[dj];

        // ---- symmetric pairwise features ----
        const float dra  = fabsf(rai - c0.y), ddec = fabsf(deci - c0.z);
        float f[8];
        f[0] = fabsf(ti_ - c0.x);
        f[1] = __builtin_amdgcn_sqrtf(fmaf(dra, dra, ddec * ddec));
        f[2] = frcp(fmaf(fabsf(mci - c0.w), 0.033333333f, 1.f));
        f[3] = __expf(fabsf(fi - c1.x) * -0.01f);
        f[4] = fminf(disti, c1.y) * frcp(fmaxf(disti, c1.y));
        f[5] = fabsf(psii - c1.z);
        f[6] = dra; f[7] = ddec;

        // ---- 8->16 GEMV + fused moments ----
        float z[16];
        float s1 = 0.f, s2 = 0.f;
        #pragma unroll
        for (int h = 0; h < 16; h++) {
            const float4 w0 = sW4[h * 2];
            const float4 w1 = sW4[h * 2 + 1];
            float zv = sEC4[h].x;
            zv = fmaf(w0.x, f[0], zv); zv = fmaf(w0.y, f[1], zv);
            zv = fmaf(w0.z, f[2], zv); zv = fmaf(w0.w, f[3], zv);
            zv = fmaf(w1.x, f[4], zv); zv = fmaf(w1.y, f[5], zv);
            zv = fmaf(w1.z, f[6], zv); zv = fmaf(w1.w, f[7], zv);
            z[h] = zv;
            s1 += zv; s2 = fmaf(zv, zv, s2);
        }
        const float mu  = s1 * 0.0625f;
        const float var = fmaf(-mu, mu, s2 * 0.0625f);
        const float inv = __builtin_amdgcn_rsqf(var + 1e-5f);

        // ---- GELU(erf) + dot(iw2) ----
        float logit = 0.f;
        #pragma unroll
        for (int h = 0; h < 16; h++) {
            const float4 c = sEC4[h];  // (b, g, bt, 0.5*w2)
            const float y = fmaf((z[h] - mu) * inv, c.y, c.z);
            logit = fmaf(y * c.w, 1.f + erf_div_sqrt2(y), logit);
        }
        float e = __expf(logit);
        // diag tile: s=32 pairs appear twice (lane a and lane a+32) -> keep half
        if (diag && s == 32 && l >= 32) e = 0.f;

        rowacc[8] += e; colacc[8] += e;
        #pragma unroll
        for (int q = 0; q < 8; q++) {
            rowacc[q] = fmaf(e, f[q], rowacc[q]);
            colacc[q] = fmaf(e, f[q], colacc[q]);
        }
        // rotate col accumulator so lane l tracks column (l + s_next) & 63
        if (t + 1 < 8) {
            const int src = (l + sstep) & 63;
            #pragma unroll
            for (int q = 0; q < 9; q++) colacc[q] = __shfl(colacc[q], src);
        }
    }

    const int s_last = sbase + sstep * 7;
    const int cfin = (l + s_last) & 63;   // true column index of colacc

    if constexpr (USE_PART) {
        // ---- single barrier: stage both sides in LDS, then coalesced plain stores ----
        #pragma unroll
        for (int q = 0; q < 9; q++) partR[q * 256 + w * 64 + l]    = rowacc[q];
        #pragma unroll
        for (int q = 0; q < 9; q++) partC[q * 256 + w * 64 + cfin] = colacc[q];
        __syncthreads();
        if (tid < 192) {
            const int sig = tid & 63;
            // slot bijection per group: row side of (ti,tj,half) -> group ti slot 2*tj+half
            //                           col side               -> group tj slot 2*ti+1-half
            // diag (half=0): slots 2g and 2g+1.  Union over all tiles = exactly 0..63.
            float* __restrict__ pr = acc + ((ti * 64 + (2 * tj + half)) * 9) * 64;
            float* __restrict__ pc = acc + ((tj * 64 + (2 * ti + 1 - half)) * 9) * 64;
            #pragma unroll
            for (int r = 0; r < 3; r++) {
                const int q = (tid >> 6) * 3 + r;
                const float* ppR = partR + q * 256 + sig;
                pr[q * 64 + sig] = ppR[0] + ppR[64] + ppR[128] + ppR[192];
                const float* ppC = partC + q * 256 + sig;
                pc[q * 64 + sig] = ppC[0] + ppC[64] + ppC[128] + ppC[192];
            }
        }
    } else {
        // ---- fallback: atomic scatter (two phases) ----
        const int stag = b & 63;
        #pragma unroll
        for (int q = 0; q < 9; q++) partR[q * 256 + w * 64 + l] = rowacc[q];
        __syncthreads();
        if (tid < 192) {
            const int sig = (tid + stag) & 63;
            #pragma unroll
            for (int r = 0; r < 3; r++) {
                const int q = (tid >> 6) * 3 + r;
                const float* pp = partR + q * 256 + sig;
                unsafeAtomicAdd(&acc[(rbase + sig) * 9 + q], pp[0] + pp[64] + pp[128] + pp[192]);
            }
        }
        __syncthreads();
        #pragma unroll
        for (int q = 0; q < 9; q++) partR[q * 256 + w * 64 + cfin] = colacc[q];
        __syncthreads();
        if (tid < 192) {
            const int sig = (tid + stag) & 63;
            #pragma unroll
            for (int r = 0; r < 3; r++) {
                const int q = (tid >> 6) * 3 + r;
                const float* pp = partR + q * 256 + sig;
                unsafeAtomicAdd(&acc[(cbase + sig) * 9 + q], pp[0] + pp[64] + pp[128] + pp[192]);
            }
        }
    }
}

// ---------------- Kernel 3 (part mode): fused slot-reduce + overlap net ----------------
// One block per 64-signal group: the group's [64 slot][9 q][64 sig] panel is
// CONTIGUOUS -> 256 threads stream it fully coalesced (cells t, t+256, t+512),
// reduce over slots into red[576], then run the overlap net for 64 signals
// in 8 passes of 8 signals (one 32-lane group per signal).
__global__ __launch_bounds__(256) void outfused_k(
    const float* __restrict__ part,
    const float* __restrict__ ow1, const float* __restrict__ ob1,
    const float* __restrict__ og1, const float* __restrict__ obt1,
    const float* __restrict__ ow2, const float* __restrict__ ob2,
    float* __restrict__ out)
{
    __shared__ float red[576];        // [q][sig] reduced sums
    __shared__ float sOw1[32 * 9];    // ow1 padded [h][9] (9 coprime 32 -> conflict-free)
    __shared__ float sOw2T[32 * 16];  // ow2 transposed [k][o]
    __shared__ float sB1[32], sG[32], sBt[32], sB2[16];
    __shared__ float h2s[8 * 33];     // per-group hidden, pad 33

    const int g = blockIdx.x;
    const int tid = threadIdx.x;

    // stage small weights
    { int h = tid >> 3, f = tid & 7; sOw1[h * 9 + f] = ow1[tid]; }          // 256 = 32*8
    { int o = tid >> 5, k = tid & 31; sOw2T[k * 16 + o] = ow2[tid]; }       // first 256 of 512
    { int idx = tid + 256; int o = idx >> 5, k = idx & 31; sOw2T[k * 16 + o] = ow2[idx]; }
    if (tid < 32) { sB1[tid] = ob1[tid]; sG[tid] = og1[tid]; sBt[tid] = obt1[tid]; }
    if (tid < 16) sB2[tid] = ob2[tid];

    // coalesced streaming reduction over 64 slots
    const float* bp = part + g * (64 * 576);
    float a0 = 0.f, a1 = 0.f, a2 = 0.f;
    #pragma unroll 4
    for (int slot = 0; slot < 64; ++slot) {
        const float* ps = bp + slot * 576;
        a0 += ps[tid];
        a1 += ps[tid + 256];
        if (tid < 64) a2 += ps[tid + 512];
    }
    red[tid] = a0; red[tid + 256] = a1; if (tid < 64) red[tid + 512] = a2;
    __syncthreads();

    const int grp = tid >> 5;   // 0..7 : one signal per 32-lane group per pass
    const int h   = tid & 31;

    for (int pass = 0; pass < 8; ++pass) {
        const int sig = pass * 8 + grp;
        const float invL = frcp(red[8 * 64 + sig]);
        float z2 = sB1[h];
        #pragma unroll
        for (int f = 0; f < 8; f++)
            z2 = fmaf(sOw1[h * 9 + f], red[f * 64 + sig] * invL, z2);
        float mu = z2;
        #pragma unroll
        for (int off = 16; off > 0; off >>= 1) mu += __shfl_xor(mu, off);
        mu *= (1.f / 32.f);
        const float d = z2 - mu;
        float var = d * d;
        #pragma unroll
        for (int off = 16; off > 0; off >>= 1) var += __shfl_xor(var, off);
        var *= (1.f / 32.f);
        const float y = d * __builtin_amdgcn_rsqf(var + 1e-5f) * sG[h] + sBt[h];
        h2s[grp * 33 + h] = 0.5f * y * (1.f + erf_div_sqrt2(y));
        __syncthreads();
        if (h < 16) {
            float o = sB2[h];
            #pragma unroll
            for (int k = 0; k < 32; k++)
                o = fmaf(sOw2T[k * 16 + h], h2s[grp * 33 + k], o);
            out[(g * 64 + sig) * 16 + h] = o;
        }
        __syncthreads();
    }
}

// ---------------- Kernel 3 (fallback mode): overlap net per row off acc[2048][9] ----
__global__ void out_k(const float* __restrict__ acc,
                      const float* __restrict__ ow1, const float* __restrict__ ob1,
                      const float* __restrict__ og1, const float* __restrict__ obt1,
                      const float* __restrict__ ow2, const float* __restrict__ ob2,
                      float* __restrict__ out)
{
    __shared__ float h2s[32];
    const int i = blockIdx.x, t = threadIdx.x;   // 64 threads
    if (t < 32) {
        const float invL = frcp(acc[i * 9 + 8]);
        float z2 = ob1[t];
        #pragma unroll
        for (int f = 0; f < 8; f++) z2 = fmaf(ow1[t * 8 + f], acc[i * 9 + f] * invL, z2);
        float mu = z2;
        #pragma unroll
        for (int off = 16; off > 0; off >>= 1) mu += __shfl_xor(mu, off);
        mu *= (1.f / 32.f);
        const float d = z2 - mu;
        float var = d * d;
        #pragma unroll
        for (int off = 16; off > 0; off >>= 1) var += __shfl_xor(var, off);
        var *= (1.f / 32.f);
        const float y = d * __builtin_amdgcn_rsqf(var + 1e-5f) * og1[t] + obt1[t];
        h2s[t] = 0.5f * y * (1.f + erf_div_sqrt2(y));
    }
    __syncthreads();
    if (t < 16) {
        float o = ob2[t];
        #pragma unroll
        for (int k = 0; k < 32; k++) o = fmaf(ow2[t * 32 + k], h2s[k], o);
        out[i * 16 + t] = o;
    }
}

extern "C" void kernel_launch(void* const* d_in, const int* in_sizes, int n_in,
                              void* d_out, int out_size, void* d_ws, size_t ws_size,
                              hipStream_t stream) {
    const float* p    = (const float*)d_in[0];
    const float* iw1  = (const float*)d_in[1];
    const float* ib1  = (const float*)d_in[2];
    const float* ig1  = (const float*)d_in[3];
    const float* ibt1 = (const float*)d_in[4];
    const float* iw2  = (const float*)d_in[5];
    // d_in[6] = ib2: uniform logit offset, softmax-invariant -> unused
    const float* ow1  = (const float*)d_in[7];
    const float* ob1  = (const float*)d_in[8];
    const float* og1  = (const float*)d_in[9];
    const float* obt1 = (const float*)d_in[10];
    const float* ow2  = (const float*)d_in[11];
    const float* ob2  = (const float*)d_in[12];

    float* dv = (float*)d_ws;                  // [2048][8]
    const bool use_part = ws_size >= (size_t)(DV_FLOATS + PART_FLOATS) * sizeof(float);

    if (use_part) {
        float* part = dv + DV_FLOATS;          // [32][64][9][64] partial sums
        derive_k<false><<<N_SIG / 256, 256, 0, stream>>>(p, dv, nullptr);
        pair_k<true><<<N_PAIR_BLOCKS, 256, 0, stream>>>(dv, iw1, ib1, ig1, ibt1, iw2, part);
        outfused_k<<<32, 256, 0, stream>>>(part, ow1, ob1, og1, obt1, ow2, ob2,
                                           (float*)d_out);
    } else {
        float* acc = dv + DV_FLOATS;           // [2048][9]
        derive_k<true><<<N_SIG / 256, 256, 0, stream>>>(p, dv, acc);
        pair_k<false><<<N_PAIR_BLOCKS, 256, 0, stream>>>(dv, iw1, ib1, ig1, ibt1, iw2, acc);
        out_k<<<N_SIG, 64, 0, stream>>>(acc, ow1, ob1, og1, obt1, ow2, ob2,
                                        (float*)d_out);
    }
}

// Round 7
// 117.610 us; speedup vs baseline: 1.2812x; 1.1650x over previous
//
#include <hip/hip_runtime.h>

#define N_SIG 2048
#define NT    32            // 2048/64 tiles per dimension
#define N_OFFDIAG_BLOCKS 992   // (32*31/2) tiles * 2 half-blocks
#define N_PAIR_BLOCKS 1024     // 992 off-diag halves + 32 full diagonal tiles
                               // == exactly 4 blocks/CU * 256 CUs at VGPR<=128
#define DV_FLOATS   (N_SIG * 8)
#define PART_FLOATS (32 * 64 * 9 * 64)   // [group][slot][q][sig] partial sums

__device__ __forceinline__ float frcp(float x) { return __builtin_amdgcn_rcpf(x); }

// erf(y / sqrt(2)) — Abramowitz–Stegun 7.1.26 with sqrt2 folded in, |err| < 1.5e-7
__device__ __forceinline__ float erf_div_sqrt2(float y) {
    const float ay = fabsf(y);
    const float t  = frcp(fmaf(0.23164454f, ay, 1.f));   // p/sqrt2, p = 0.3275911
    const float p  = t * fmaf(t, fmaf(t, fmaf(t, fmaf(t, 1.061405429f, -1.453152027f),
                                              1.421413741f), -0.284496736f), 0.254829592f);
    const float e  = __expf(-0.5f * ay * ay);
    return copysignf(fmaf(-p, e, 1.f), y);
}

// ---------------- Kernel 1: per-signal derived quantities (+ zero acc in atomic mode) ----
template<bool ZERO_ACC>
__global__ void derive_k(const float* __restrict__ p, float* __restrict__ dv,
                         float* __restrict__ acc) {
    int j = blockIdx.x * blockDim.x + threadIdx.x;
    if (j >= N_SIG) return;
    if constexpr (ZERO_ACC) {
        #pragma unroll
        for (int k = 0; k < 9; k++) acc[j * 9 + k] = 0.f;
    }
    const float* pj = p + j * 15;
    float m1 = pj[0] * 95.f + 5.f, m2 = pj[1] * 95.f + 5.f;
    float mc = powf(m1 * m2, 0.6f) / powf(m1 + m2, 0.2f);
    float fisco = 220.f / (m1 + m2);
    float dist = pj[2] * 2950.f + 50.f;
    float4* o = (float4*)(dv + j * 8);
    o[0] = make_float4(pj[5], pj[3], pj[4], mc);   // t, ra, dec, mc
    o[1] = make_float4(fisco, dist, pj[7], 0.f);   // fisco, dist, psi, pad
}

// ---------------- Kernel 2: symmetric pair tiles (EXACT R2 body) ----------------
// REGALLOC CLIFF LOG — do not "improve" this loop without re-checking VGPR:
//   R2 (this body):           VGPR 128 -> 4 blocks/CU, perfect 1024 fill, ~37us
//   R3 scalar-load weights:   VGPR 52, serialized, 53us
//   R4 dual-column:           VGPR 140 -> 3 blocks/CU, 1.33x fill tax, 48us
//   R5 global cols + csum-s1: VGPR 136 -> 3 blocks/CU, 49us
// VALU-issue is ~28us OR-busy in every variant; only occupancy x fill moved time.
// OUT-STAGE LOG: 32-block fused out kernel (R3-R6) = +17us vs 2048-block out_k
// (32/256 CUs busy, cross-XCD L2-miss latency, no TLP). Keep out_k.
// NOTE: no min-waves arg! (256,4) capped VGPR at 128 -> allocator squeezed to 64
// -> spill -> 1.1 GB HBM scratch traffic (prior session rounds 5/6).
template<bool USE_PART>
__global__ __launch_bounds__(256) void pair_k(
    const float* __restrict__ dv,
    const float* __restrict__ iw1, const float* __restrict__ ib1,
    const float* __restrict__ ig1, const float* __restrict__ ibt1,
    const float* __restrict__ iw2,
    float* __restrict__ acc)   // part (part mode) or acc (atomic mode)
{
    __shared__ float4 sColA[64], sColB[64];
    __shared__ __align__(16) float sW1[128];   // iw1 [16][8]
    __shared__ __align__(16) float sEC[64];    // per-h (b1, g1, bt1, 0.5*w2)
    __shared__ float partR[9 * 256];           // [q][wave][lane]
    __shared__ float partC[USE_PART ? 9 * 256 : 1];

    // ---- tile decode: 992 off-diag half-blocks, then 32 full diag blocks ----
    const int b = blockIdx.x;
    int ti, tj, half;
    bool diag;
    if (b < N_OFFDIAG_BLOCKS) {
        const int tileId = b >> 1;
        half = b & 1;
        int k = tileId, row = 0;
        while (k >= NT - 1 - row) { k -= NT - 1 - row; row++; }
        ti = row; tj = row + 1 + k;
        diag = false;
    } else {
        ti = tj = b - N_OFFDIAG_BLOCKS;
        half = 0;
        diag = true;
    }
    const int rbase = ti * 64, cbase = tj * 64;

    const int tid = threadIdx.x;
    const float4* dv4 = (const float4*)dv;

    if (tid < 64)  { sColA[tid] = dv4[(cbase + tid) * 2]; sColB[tid] = dv4[(cbase + tid) * 2 + 1]; }
    if (tid >= 64 && tid < 192) sW1[tid - 64] = iw1[tid - 64];
    if (tid >= 192 && tid < 208) {
        int h = tid - 192;
        sEC[h * 4 + 0] = ib1[h]; sEC[h * 4 + 1] = ig1[h];
        sEC[h * 4 + 2] = ibt1[h]; sEC[h * 4 + 3] = 0.5f * iw2[h];
    }
    __syncthreads();

    const int w = tid >> 6, l = tid & 63;
    const int gi = rbase + l;
    const float4 r0 = dv4[gi * 2], r1 = dv4[gi * 2 + 1];
    const float ti_ = r0.x, rai = r0.y, deci = r0.z, mci = r0.w;
    const float fi = r1.x, disti = r1.y, psii = r1.z;

    // off-diag: vwave V=half*4+w covers s in {V+8t}, t=0..7 -> s 0..63 over 8 vwaves
    // diag:     wave w covers s in {w+1+4t}, t=0..7         -> s 1..32 over 4 waves
    const int sstep = diag ? 4 : 8;
    const int sbase = diag ? (w + 1) : (half * 4 + w);

    float rowacc[9], colacc[9];
    #pragma unroll
    for (int q = 0; q < 9; q++) { rowacc[q] = 0.f; colacc[q] = 0.f; }

    const float4* sW4  = (const float4*)sW1;
    const float4* sEC4 = (const float4*)sEC;

    for (int t = 0; t < 8; t++) {
        const int s  = sbase + sstep * t;
        const int dj = (l + s) & 63;
        const float4 c0 = sColA[dj], c1 = sColB[dj];

        // ---- symmetric pairwise features ----
        const float dra  = fabsf(rai - c0.y), ddec = fabsf(deci - c0.z);
        float f[8];
        f[0] = fabsf(ti_ - c0.x);
        f[1] = __builtin_amdgcn_sqrtf(fmaf(dra, dra, ddec * ddec));
        f[2] = frcp(fmaf(fabsf(mci - c0.w), 0.033333333f, 1.f));
        f[3] = __expf(fabsf(fi - c1.x) * -0.01f);
        f[4] = fminf(disti, c1.y) * frcp(fmaxf(disti, c1.y));
        f[5] = fabsf(psii - c1.z);
        f[6] = dra; f[7] = ddec;

        // ---- 8->16 GEMV + fused moments ----
        float z[16];
        float s1 = 0.f, s2 = 0.f;
        #pragma unroll
        for (int h = 0; h < 16; h++) {
            const float4 w0 = sW4[h * 2];
            const float4 w1 = sW4[h * 2 + 1];
            float zv = sEC4[h].x;
            zv = fmaf(w0.x, f[0], zv); zv = fmaf(w0.y, f[1], zv);
            zv = fmaf(w0.z, f[2], zv); zv = fmaf(w0.w, f[3], zv);
            zv = fmaf(w1.x, f[4], zv); zv = fmaf(w1.y, f[5], zv);
            zv = fmaf(w1.z, f[6], zv); zv = fmaf(w1.w, f[7], zv);
            z[h] = zv;
            s1 += zv; s2 = fmaf(zv, zv, s2);
        }
        const float mu  = s1 * 0.0625f;
        const float var = fmaf(-mu, mu, s2 * 0.0625f);
        const float inv = __builtin_amdgcn_rsqf(var + 1e-5f);

        // ---- GELU(erf) + dot(iw2) ----
        float logit = 0.f;
        #pragma unroll
        for (int h = 0; h < 16; h++) {
            const float4 c = sEC4[h];  // (b, g, bt, 0.5*w2)
            const float y = fmaf((z[h] - mu) * inv, c.y, c.z);
            logit = fmaf(y * c.w, 1.f + erf_div_sqrt2(y), logit);
        }
        float e = __expf(logit);
        // diag tile: s=32 pairs appear twice (lane a and lane a+32) -> keep half
        if (diag && s == 32 && l >= 32) e = 0.f;

        rowacc[8] += e; colacc[8] += e;
        #pragma unroll
        for (int q = 0; q < 8; q++) {
            rowacc[q] = fmaf(e, f[q], rowacc[q]);
            colacc[q] = fmaf(e, f[q], colacc[q]);
        }
        // rotate col accumulator so lane l tracks column (l + s_next) & 63
        if (t + 1 < 8) {
            const int src = (l + sstep) & 63;
            #pragma unroll
            for (int q = 0; q < 9; q++) colacc[q] = __shfl(colacc[q], src);
        }
    }

    const int s_last = sbase + sstep * 7;
    const int cfin = (l + s_last) & 63;   // true column index of colacc

    if constexpr (USE_PART) {
        // ---- single barrier: stage both sides in LDS, then coalesced plain stores ----
        #pragma unroll
        for (int q = 0; q < 9; q++) partR[q * 256 + w * 64 + l]    = rowacc[q];
        #pragma unroll
        for (int q = 0; q < 9; q++) partC[q * 256 + w * 64 + cfin] = colacc[q];
        __syncthreads();
        if (tid < 192) {
            const int sig = tid & 63;
            // slot bijection per group: row side of (ti,tj,half) -> group ti slot 2*tj+half
            //                           col side               -> group tj slot 2*ti+1-half
            // diag (half=0): slots 2g and 2g+1.  Union over all tiles = exactly 0..63.
            float* __restrict__ pr = acc + ((ti * 64 + (2 * tj + half)) * 9) * 64;
            float* __restrict__ pc = acc + ((tj * 64 + (2 * ti + 1 - half)) * 9) * 64;
            #pragma unroll
            for (int r = 0; r < 3; r++) {
                const int q = (tid >> 6) * 3 + r;
                const float* ppR = partR + q * 256 + sig;
                pr[q * 64 + sig] = ppR[0] + ppR[64] + ppR[128] + ppR[192];
                const float* ppC = partC + q * 256 + sig;
                pc[q * 64 + sig] = ppC[0] + ppC[64] + ppC[128] + ppC[192];
            }
        }
    } else {
        // ---- fallback: atomic scatter (two phases) ----
        const int stag = b & 63;
        #pragma unroll
        for (int q = 0; q < 9; q++) partR[q * 256 + w * 64 + l] = rowacc[q];
        __syncthreads();
        if (tid < 192) {
            const int sig = (tid + stag) & 63;
            #pragma unroll
            for (int r = 0; r < 3; r++) {
                const int q = (tid >> 6) * 3 + r;
                const float* pp = partR + q * 256 + sig;
                unsafeAtomicAdd(&acc[(rbase + sig) * 9 + q], pp[0] + pp[64] + pp[128] + pp[192]);
            }
        }
        __syncthreads();
        #pragma unroll
        for (int q = 0; q < 9; q++) partR[q * 256 + w * 64 + cfin] = colacc[q];
        __syncthreads();
        if (tid < 192) {
            const int sig = (tid + stag) & 63;
            #pragma unroll
            for (int r = 0; r < 3; r++) {
                const int q = (tid >> 6) * 3 + r;
                const float* pp = partR + q * 256 + sig;
                unsafeAtomicAdd(&acc[(cbase + sig) * 9 + q], pp[0] + pp[64] + pp[128] + pp[192]);
            }
        }
    }
}

// ---------------- Kernel 3: slot-reduce (part mode) + overlap net per row ----------------
// 2048 blocks x 64 threads. Part-mode reads are uncoalesced (lane=slot, stride
// 2304B) but 2048 independent blocks give enough TLP to hide L2/L3 latency —
// measured 17us FASTER in total than the 32-block coalesced fused version
// (which kept only 32/256 CUs busy on cross-XCD data).
template<bool USE_PART>
__global__ void out_k(const float* __restrict__ accp,
                      const float* __restrict__ ow1, const float* __restrict__ ob1,
                      const float* __restrict__ og1, const float* __restrict__ obt1,
                      const float* __restrict__ ow2, const float* __restrict__ ob2,
                      float* __restrict__ out)
{
    __shared__ float h2s[32];
    const int t = threadIdx.x;   // 64 threads
    int i;
    float a9[9];
    if constexpr (USE_PART) {
        const int b = blockIdx.x;
        i = (b & 7) * 256 + (b >> 3);        // XCD-grouped sig mapping (L2 locality)
        const int g = i >> 6, sig = i & 63;
        // lane t = slot; xor-reduce leaves the full sum in every lane
        #pragma unroll
        for (int q = 0; q < 9; q++) {
            float v = accp[(((g * 64 + t) * 9) + q) * 64 + sig];
            #pragma unroll
            for (int off = 32; off > 0; off >>= 1) v += __shfl_xor(v, off);
            a9[q] = v;
        }
    } else {
        i = blockIdx.x;
        if (t < 32) {
            #pragma unroll
            for (int q = 0; q < 9; q++) a9[q] = accp[i * 9 + q];
        }
    }
    if (t < 32) {
        const float invL = frcp(a9[8]);
        float z2 = ob1[t];
        #pragma unroll
        for (int f = 0; f < 8; f++) z2 = fmaf(ow1[t * 8 + f], a9[f] * invL, z2);
        float mu = z2;
        #pragma unroll
        for (int off = 16; off > 0; off >>= 1) mu += __shfl_xor(mu, off);
        mu *= (1.f / 32.f);
        const float d = z2 - mu;
        float var = d * d;
        #pragma unroll
        for (int off = 16; off > 0; off >>= 1) var += __shfl_xor(var, off);
        var *= (1.f / 32.f);
        const float y = d * __builtin_amdgcn_rsqf(var + 1e-5f) * og1[t] + obt1[t];
        h2s[t] = 0.5f * y * (1.f + erf_div_sqrt2(y));
    }
    __syncthreads();
    if (t < 16) {
        float o = ob2[t];
        #pragma unroll
        for (int k = 0; k < 32; k++) o = fmaf(ow2[t * 32 + k], h2s[k], o);
        out[i * 16 + t] = o;
    }
}

extern "C" void kernel_launch(void* const* d_in, const int* in_sizes, int n_in,
                              void* d_out, int out_size, void* d_ws, size_t ws_size,
                              hipStream_t stream) {
    const float* p    = (const float*)d_in[0];
    const float* iw1  = (const float*)d_in[1];
    const float* ib1  = (const float*)d_in[2];
    const float* ig1  = (const float*)d_in[3];
    const float* ibt1 = (const float*)d_in[4];
    const float* iw2  = (const float*)d_in[5];
    // d_in[6] = ib2: uniform logit offset, softmax-invariant -> unused
    const float* ow1  = (const float*)d_in[7];
    const float* ob1  = (const float*)d_in[8];
    const float* og1  = (const float*)d_in[9];
    const float* obt1 = (const float*)d_in[10];
    const float* ow2  = (const float*)d_in[11];
    const float* ob2  = (const float*)d_in[12];

    float* dv = (float*)d_ws;                  // [2048][8]
    const bool use_part = ws_size >= (size_t)(DV_FLOATS + PART_FLOATS) * sizeof(float);

    if (use_part) {
        float* part = dv + DV_FLOATS;          // [32][64][9][64] partial sums
        derive_k<false><<<N_SIG / 256, 256, 0, stream>>>(p, dv, nullptr);
        pair_k<true><<<N_PAIR_BLOCKS, 256, 0, stream>>>(dv, iw1, ib1, ig1, ibt1, iw2, part);
        out_k<true><<<N_SIG, 64, 0, stream>>>(part, ow1, ob1, og1, obt1, ow2, ob2,
                                              (float*)d_out);
    } else {
        float* acc = dv + DV_FLOATS;           // [2048][9]
        derive_k<true><<<N_SIG / 256, 256, 0, stream>>>(p, dv, acc);
        pair_k<false><<<N_PAIR_BLOCKS, 256, 0, stream>>>(dv, iw1, ib1, ig1, ibt1, iw2, acc);
        out_k<false><<<N_SIG, 64, 0, stream>>>(acc, ow1, ob1, og1, obt1, ow2, ob2,
                                               (float*)d_out);
    }
}

// Round 8
// 116.080 us; speedup vs baseline: 1.2981x; 1.0132x over previous
//
#include <hip/hip_runtime.h>

#define N_SIG 2048
#define NT    32            // 2048/64 tiles per dimension
#define N_OFFDIAG_BLOCKS 992   // (32*31/2) tiles * 2 half-blocks
#define N_PAIR_BLOCKS 1024     // 992 off-diag halves + 32 full diagonal tiles
                               // == exactly 4 blocks/CU * 256 CUs at VGPR<=128
#define PART_FLOATS (32 * 64 * 9 * 64)   // [group][slot][q][sig] partial sums

__device__ __forceinline__ float frcp(float x) { return __builtin_amdgcn_rcpf(x); }

// erf(y / sqrt(2)) — Abramowitz–Stegun 7.1.26 with sqrt2 folded in, |err| < 1.5e-7
__device__ __forceinline__ float erf_div_sqrt2(float y) {
    const float ay = fabsf(y);
    const float t  = frcp(fmaf(0.23164454f, ay, 1.f));   // p/sqrt2, p = 0.3275911
    const float p  = t * fmaf(t, fmaf(t, fmaf(t, fmaf(t, 1.061405429f, -1.453152027f),
                                              1.421413741f), -0.284496736f), 0.254829592f);
    const float e  = __expf(-0.5f * ay * ay);
    return copysignf(fmaf(-p, e, 1.f), y);
}

// per-signal derived quantities, inline (replaces the old derive_k kernel):
// {t, ra, dec, mc, fisco, dist, psi} from the raw 15-param row.
__device__ __forceinline__ void derive_sig(const float* __restrict__ pj,
                                           float& t_, float& ra, float& dec, float& mc,
                                           float& fisco, float& dist, float& psi) {
    const float m1 = fmaf(pj[0], 95.f, 5.f), m2 = fmaf(pj[1], 95.f, 5.f);
    const float msum = m1 + m2;
    // mc = (m1*m2)^0.6 / (m1+m2)^0.2 = exp2(0.6*log2(m1*m2) - 0.2*log2(m1+m2))
    mc   = exp2f(fmaf(0.6f, __log2f(m1 * m2), -0.2f * __log2f(msum)));
    fisco = 220.f / msum;
    dist  = fmaf(pj[2], 2950.f, 50.f);
    t_ = pj[5]; ra = pj[3]; dec = pj[4]; psi = pj[7];
}

// ---------------- fallback-mode helper: zero acc[2048][9] ----------------
__global__ void zeroacc_k(float* __restrict__ acc) {
    int i = blockIdx.x * blockDim.x + threadIdx.x;
    if (i < N_SIG * 9) acc[i] = 0.f;
}

// ---------------- Kernel 1: symmetric pair tiles (R2 loop body, derive fused in prologue) ----
// REGALLOC CLIFF LOG — do not "improve" the main loop without re-checking VGPR:
//   R2 (this body):           VGPR 128 -> 4 blocks/CU, perfect 1024 fill, ~37us
//   R3 scalar-load weights:   VGPR 52, serialized, 53us
//   R4 dual-column:           VGPR 140 -> 3 blocks/CU, 1.33x fill tax, 48us
//   R5 global cols + csum-s1: VGPR 136 -> 3 blocks/CU, 49us
// VALU-issue is ~28us OR-busy in every variant; only occupancy x fill moved time.
// OUT-STAGE LOG: 32-block fused out kernel (R3-R6) = +17us vs 2048-block out_k
// (32/256 CUs busy, cross-XCD L2-miss latency, no TLP). Keep out_k.
// R8: derive_k merged into the PROLOGUE (per-block, outside the steady loop, so
// loop regalloc is untouched): removes one dispatch + gap + the dv round-trip.
// NOTE: no min-waves arg! (256,4) capped VGPR at 128 -> allocator squeezed to 64
// -> spill -> 1.1 GB HBM scratch traffic (prior session rounds 5/6).
template<bool USE_PART>
__global__ __launch_bounds__(256) void pair_k(
    const float* __restrict__ p,
    const float* __restrict__ iw1, const float* __restrict__ ib1,
    const float* __restrict__ ig1, const float* __restrict__ ibt1,
    const float* __restrict__ iw2,
    float* __restrict__ acc)   // part (part mode) or acc (atomic mode)
{
    __shared__ float4 sColA[64], sColB[64];
    __shared__ __align__(16) float sW1[128];   // iw1 [16][8]
    __shared__ __align__(16) float sEC[64];    // per-h (b1, g1, bt1, 0.5*w2)
    __shared__ float partR[9 * 256];           // [q][wave][lane]
    __shared__ float partC[USE_PART ? 9 * 256 : 1];

    // ---- tile decode: 992 off-diag half-blocks, then 32 full diag blocks ----
    const int b = blockIdx.x;
    int ti, tj, half;
    bool diag;
    if (b < N_OFFDIAG_BLOCKS) {
        const int tileId = b >> 1;
        half = b & 1;
        int k = tileId, row = 0;
        while (k >= NT - 1 - row) { k -= NT - 1 - row; row++; }
        ti = row; tj = row + 1 + k;
        diag = false;
    } else {
        ti = tj = b - N_OFFDIAG_BLOCKS;
        half = 0;
        diag = true;
    }
    const int rbase = ti * 64, cbase = tj * 64;

    const int tid = threadIdx.x;
    const int w = tid >> 6, l = tid & 63;

    // ---- prologue: derive row signal (all threads) + stage cols/weights ----
    float ti_, rai, deci, mci, fi, disti, psii;
    derive_sig(p + (rbase + l) * 15, ti_, rai, deci, mci, fi, disti, psii);

    if (tid < 64) {
        float ct, cra, cdec, cmc, cfi, cdist, cpsi;
        derive_sig(p + (cbase + tid) * 15, ct, cra, cdec, cmc, cfi, cdist, cpsi);
        sColA[tid] = make_float4(ct, cra, cdec, cmc);
        sColB[tid] = make_float4(cfi, cdist, cpsi, 0.f);
    }
    if (tid >= 64 && tid < 192) sW1[tid - 64] = iw1[tid - 64];
    if (tid >= 192 && tid < 208) {
        int h = tid - 192;
        sEC[h * 4 + 0] = ib1[h]; sEC[h * 4 + 1] = ig1[h];
        sEC[h * 4 + 2] = ibt1[h]; sEC[h * 4 + 3] = 0.5f * iw2[h];
    }
    __syncthreads();

    // off-diag: vwave V=half*4+w covers s in {V+8t}, t=0..7 -> s 0..63 over 8 vwaves
    // diag:     wave w covers s in {w+1+4t}, t=0..7         -> s 1..32 over 4 waves
    const int sstep = diag ? 4 : 8;
    const int sbase = diag ? (w + 1) : (half * 4 + w);

    float rowacc[9], colacc[9];
    #pragma unroll
    for (int q = 0; q < 9; q++) { rowacc[q] = 0.f; colacc[q] = 0.f; }

    const float4* sW4  = (const float4*)sW1;
    const float4* sEC4 = (const float4*)sEC;

    for (int t = 0; t < 8; t++) {
        const int s  = sbase + sstep * t;
        const int dj = (l + s) & 63;
        const float4 c0 = sColA[dj], c1 = sColB[dj];

        // ---- symmetric pairwise features ----
        const float dra  = fabsf(rai - c0.y), ddec = fabsf(deci - c0.z);
        float f[8];
        f[0] = fabsf(ti_ - c0.x);
        f[1] = __builtin_amdgcn_sqrtf(fmaf(dra, dra, ddec * ddec));
        f[2] = frcp(fmaf(fabsf(mci - c0.w), 0.033333333f, 1.f));
        f[3] = __expf(fabsf(fi - c1.x) * -0.01f);
        f[4] = fminf(disti, c1.y) * frcp(fmaxf(disti, c1.y));
        f[5] = fabsf(psii - c1.z);
        f[6] = dra; f[7] = ddec;

        // ---- 8->16 GEMV + fused moments ----
        float z[16];
        float s1 = 0.f, s2 = 0.f;
        #pragma unroll
        for (int h = 0; h < 16; h++) {
            const float4 w0 = sW4[h * 2];
            const float4 w1 = sW4[h * 2 + 1];
            float zv = sEC4[h].x;
            zv = fmaf(w0.x, f[0], zv); zv = fmaf(w0.y, f[1], zv);
            zv = fmaf(w0.z, f[2], zv); zv = fmaf(w0.w, f[3], zv);
            zv = fmaf(w1.x, f[4], zv); zv = fmaf(w1.y, f[5], zv);
            zv = fmaf(w1.z, f[6], zv); zv = fmaf(w1.w, f[7], zv);
            z[h] = zv;
            s1 += zv; s2 = fmaf(zv, zv, s2);
        }
        const float mu  = s1 * 0.0625f;
        const float var = fmaf(-mu, mu, s2 * 0.0625f);
        const float inv = __builtin_amdgcn_rsqf(var + 1e-5f);

        // ---- GELU(erf) + dot(iw2) ----
        float logit = 0.f;
        #pragma unroll
        for (int h = 0; h < 16; h++) {
            const float4 c = sEC4[h];  // (b, g, bt, 0.5*w2)
            const float y = fmaf((z[h] - mu) * inv, c.y, c.z);
            logit = fmaf(y * c.w, 1.f + erf_div_sqrt2(y), logit);
        }
        float e = __expf(logit);
        // diag tile: s=32 pairs appear twice (lane a and lane a+32) -> keep half
        if (diag && s == 32 && l >= 32) e = 0.f;

        rowacc[8] += e; colacc[8] += e;
        #pragma unroll
        for (int q = 0; q < 8; q++) {
            rowacc[q] = fmaf(e, f[q], rowacc[q]);
            colacc[q] = fmaf(e, f[q], colacc[q]);
        }
        // rotate col accumulator so lane l tracks column (l + s_next) & 63
        if (t + 1 < 8) {
            const int src = (l + sstep) & 63;
            #pragma unroll
            for (int q = 0; q < 9; q++) colacc[q] = __shfl(colacc[q], src);
        }
    }

    const int s_last = sbase + sstep * 7;
    const int cfin = (l + s_last) & 63;   // true column index of colacc

    if constexpr (USE_PART) {
        // ---- single barrier: stage both sides in LDS, then coalesced plain stores ----
        #pragma unroll
        for (int q = 0; q < 9; q++) partR[q * 256 + w * 64 + l]    = rowacc[q];
        #pragma unroll
        for (int q = 0; q < 9; q++) partC[q * 256 + w * 64 + cfin] = colacc[q];
        __syncthreads();
        if (tid < 192) {
            const int sig = tid & 63;
            // slot bijection per group: row side of (ti,tj,half) -> group ti slot 2*tj+half
            //                           col side               -> group tj slot 2*ti+1-half
            // diag (half=0): slots 2g and 2g+1.  Union over all tiles = exactly 0..63.
            float* __restrict__ pr = acc + ((ti * 64 + (2 * tj + half)) * 9) * 64;
            float* __restrict__ pc = acc + ((tj * 64 + (2 * ti + 1 - half)) * 9) * 64;
            #pragma unroll
            for (int r = 0; r < 3; r++) {
                const int q = (tid >> 6) * 3 + r;
                const float* ppR = partR + q * 256 + sig;
                pr[q * 64 + sig] = ppR[0] + ppR[64] + ppR[128] + ppR[192];
                const float* ppC = partC + q * 256 + sig;
                pc[q * 64 + sig] = ppC[0] + ppC[64] + ppC[128] + ppC[192];
            }
        }
    } else {
        // ---- fallback: atomic scatter (two phases) ----
        const int stag = b & 63;
        #pragma unroll
        for (int q = 0; q < 9; q++) partR[q * 256 + w * 64 + l] = rowacc[q];
        __syncthreads();
        if (tid < 192) {
            const int sig = (tid + stag) & 63;
            #pragma unroll
            for (int r = 0; r < 3; r++) {
                const int q = (tid >> 6) * 3 + r;
                const float* pp = partR + q * 256 + sig;
                unsafeAtomicAdd(&acc[(rbase + sig) * 9 + q], pp[0] + pp[64] + pp[128] + pp[192]);
            }
        }
        __syncthreads();
        #pragma unroll
        for (int q = 0; q < 9; q++) partR[q * 256 + w * 64 + cfin] = colacc[q];
        __syncthreads();
        if (tid < 192) {
            const int sig = (tid + stag) & 63;
            #pragma unroll
            for (int r = 0; r < 3; r++) {
                const int q = (tid >> 6) * 3 + r;
                const float* pp = partR + q * 256 + sig;
                unsafeAtomicAdd(&acc[(cbase + sig) * 9 + q], pp[0] + pp[64] + pp[128] + pp[192]);
            }
        }
    }
}

// ---------------- Kernel 2: slot-reduce (part mode) + overlap net per row ----------------
// 2048 blocks x 64 threads. Part-mode reads are uncoalesced (lane=slot, stride
// 2304B) but 2048 independent blocks give enough TLP to hide L2/L3 latency —
// measured 17us FASTER in total than the 32-block coalesced fused version
// (which kept only 32/256 CUs busy on cross-XCD data).
template<bool USE_PART>
__global__ void out_k(const float* __restrict__ accp,
                      const float* __restrict__ ow1, const float* __restrict__ ob1,
                      const float* __restrict__ og1, const float* __restrict__ obt1,
                      const float* __restrict__ ow2, const float* __restrict__ ob2,
                      float* __restrict__ out)
{
    __shared__ float h2s[32];
    const int t = threadIdx.x;   // 64 threads
    int i;
    float a9[9];
    if constexpr (USE_PART) {
        const int b = blockIdx.x;
        i = (b & 7) * 256 + (b >> 3);        // XCD-grouped sig mapping (L2 locality)
        const int g = i >> 6, sig = i & 63;
        // lane t = slot; xor-reduce leaves the full sum in every lane
        #pragma unroll
        for (int q = 0; q < 9; q++) {
            float v = accp[(((g * 64 + t) * 9) + q) * 64 + sig];
            #pragma unroll
            for (int off = 32; off > 0; off >>= 1) v += __shfl_xor(v, off);
            a9[q] = v;
        }
    } else {
        i = blockIdx.x;
        if (t < 32) {
            #pragma unroll
            for (int q = 0; q < 9; q++) a9[q] = accp[i * 9 + q];
        }
    }
    if (t < 32) {
        const float invL = frcp(a9[8]);
        float z2 = ob1[t];
        #pragma unroll
        for (int f = 0; f < 8; f++) z2 = fmaf(ow1[t * 8 + f], a9[f] * invL, z2);
        float mu = z2;
        #pragma unroll
        for (int off = 16; off > 0; off >>= 1) mu += __shfl_xor(mu, off);
        mu *= (1.f / 32.f);
        const float d = z2 - mu;
        float var = d * d;
        #pragma unroll
        for (int off = 16; off > 0; off >>= 1) var += __shfl_xor(var, off);
        var *= (1.f / 32.f);
        const float y = d * __builtin_amdgcn_rsqf(var + 1e-5f) * og1[t] + obt1[t];
        h2s[t] = 0.5f * y * (1.f + erf_div_sqrt2(y));
    }
    __syncthreads();
    if (t < 16) {
        float o = ob2[t];
        #pragma unroll
        for (int k = 0; k < 32; k++) o = fmaf(ow2[t * 32 + k], h2s[k], o);
        out[i * 16 + t] = o;
    }
}

extern "C" void kernel_launch(void* const* d_in, const int* in_sizes, int n_in,
                              void* d_out, int out_size, void* d_ws, size_t ws_size,
                              hipStream_t stream) {
    const float* p    = (const float*)d_in[0];
    const float* iw1  = (const float*)d_in[1];
    const float* ib1  = (const float*)d_in[2];
    const float* ig1  = (const float*)d_in[3];
    const float* ibt1 = (const float*)d_in[4];
    const float* iw2  = (const float*)d_in[5];
    // d_in[6] = ib2: uniform logit offset, softmax-invariant -> unused
    const float* ow1  = (const float*)d_in[7];
    const float* ob1  = (const float*)d_in[8];
    const float* og1  = (const float*)d_in[9];
    const float* obt1 = (const float*)d_in[10];
    const float* ow2  = (const float*)d_in[11];
    const float* ob2  = (const float*)d_in[12];

    const bool use_part = ws_size >= (size_t)PART_FLOATS * sizeof(float);

    if (use_part) {
        float* part = (float*)d_ws;            // [32][64][9][64] partial sums
        pair_k<true><<<N_PAIR_BLOCKS, 256, 0, stream>>>(p, iw1, ib1, ig1, ibt1, iw2, part);
        out_k<true><<<N_SIG, 64, 0, stream>>>(part, ow1, ob1, og1, obt1, ow2, ob2,
                                              (float*)d_out);
    } else {
        float* acc = (float*)d_ws;             // [2048][9]
        zeroacc_k<<<(N_SIG * 9 + 255) / 256, 256, 0, stream>>>(acc);
        pair_k<false><<<N_PAIR_BLOCKS, 256, 0, stream>>>(p, iw1, ib1, ig1, ibt1, iw2, acc);
        out_k<false><<<N_SIG, 64, 0, stream>>>(acc, ow1, ob1, og1, obt1, ow2, ob2,
                                               (float*)d_out);
    }
}